// Round 1
// baseline (69.507 us; speedup 1.0000x reference)
//
#include <hip/hip_runtime.h>
#include <hip/hip_bf16.h>

// Reference returns x unchanged (the attention path is dead code, faithful to
// the original torch module). Output = input x: [8, 64, 4096] float32.
// Optimal implementation: a device-to-device copy of d_in[0] -> d_out.

extern "C" void kernel_launch(void* const* d_in, const int* in_sizes, int n_in,
                              void* d_out, int out_size, void* d_ws, size_t ws_size,
                              hipStream_t stream) {
    const float* x = (const float*)d_in[0];
    float* out = (float*)d_out;
    const size_t nbytes = (size_t)out_size * sizeof(float);  // 2,097,152 * 4 = 8 MiB
    hipMemcpyAsync(out, x, nbytes, hipMemcpyDeviceToDevice, stream);
}